// Round 1
// baseline (867.766 us; speedup 1.0000x reference)
//
#include <hip/hip_runtime.h>
#include <math.h>

#define I_SZ   4096
#define H_SZ   3584
#define O_SZ   512
#define TOTAL  8192
#define HO     4096   // TOTAL - I_SZ (rows that actually update)
#define BETA   0.1f
#define LR     0.5f
#define T1C    20
#define T2C    4

// ---------------- init: state buffers ----------------
// s_a = d_out: [x, 0...0]; s_b: input slice = x (tail written by step 1)
__global__ void k_init(const float* __restrict__ x, float* __restrict__ s_a,
                       float* __restrict__ s_b) {
    int i = blockIdx.x * 256 + threadIdx.x;
    if (i < I_SZ) { float v = x[i]; s_a[i] = v; s_b[i] = v; }
    else if (i < TOTAL) { s_a[i] = 0.0f; }
}

// ---------------- build Wsym_sub (fast path) ----------------
// Ws[r][j] = 0.5*(W[I_SZ+r][j] + W[j][I_SZ+r]),  r in [0,HO), j in [0,TOTAL)
__global__ void k_build(const float* __restrict__ W, float* __restrict__ Ws) {
    __shared__ float tb[32][33];
    int j0 = blockIdx.x * 32;
    int r0 = blockIdx.y * 32;
    int tx = threadIdx.x;   // 0..31
    int ty = threadIdx.y;   // 0..7
    #pragma unroll
    for (int k = 0; k < 4; k++) {
        int a = ty + 8 * k;
        tb[a][tx] = W[(size_t)(j0 + a) * TOTAL + (I_SZ + r0 + tx)];
    }
    __syncthreads();
    #pragma unroll
    for (int k = 0; k < 4; k++) {
        int ri = ty + 8 * k;
        int r = r0 + ri, j = j0 + tx;
        float direct = W[(size_t)(I_SZ + r) * TOTAL + j];
        Ws[(size_t)r * TOTAL + j] = 0.5f * (direct + tb[tx][ri]);
    }
}

// ---------------- softmax correction (beta phase) ----------------
// corr[t] = -BETA * (softmax(logits)[t]*t_sum - t_eff[t]),  logits = s_cur[out slice]
__global__ void k_softmax(const float* __restrict__ s_cur,
                          const float* __restrict__ target,
                          const float* __restrict__ mask,
                          float* __restrict__ corr) {
    __shared__ float buf[8];
    __shared__ float s_m, s_z, s_ts;
    int t = threadIdx.x;  // 512 threads
    float logit = s_cur[I_SZ + H_SZ + t];
    float te = mask[t] * target[t];

    float m = logit;
    for (int off = 32; off > 0; off >>= 1) m = fmaxf(m, __shfl_down(m, off, 64));
    if ((t & 63) == 0) buf[t >> 6] = m;
    __syncthreads();
    if (t == 0) { float v = buf[0]; for (int i = 1; i < 8; i++) v = fmaxf(v, buf[i]); s_m = v; }
    __syncthreads();

    float e = expf(logit - s_m);
    float z = e;
    for (int off = 32; off > 0; off >>= 1) z += __shfl_down(z, off, 64);
    if ((t & 63) == 0) buf[t >> 6] = z;
    __syncthreads();
    if (t == 0) { float v = 0.f; for (int i = 0; i < 8; i++) v += buf[i]; s_z = v; }
    __syncthreads();

    float ts = te;
    for (int off = 32; off > 0; off >>= 1) ts += __shfl_down(ts, off, 64);
    if ((t & 63) == 0) buf[t >> 6] = ts;
    __syncthreads();
    if (t == 0) { float v = 0.f; for (int i = 0; i < 8; i++) v += buf[i]; s_ts = v; }
    __syncthreads();

    float p = e / s_z;
    corr[t] = -BETA * (p * s_ts - te);
}

// ---------------- fused matvec + update (fast path) ----------------
// one block (256 thr) per row r in [0,HO); g = Ws[r,:].s_cur (Ws has the 0.5 baked in)
template <bool WITH_CORR>
__global__ void k_step(const float* __restrict__ Ws, const float* __restrict__ s_cur,
                       float* __restrict__ s_next, const float* __restrict__ corr) {
    int r = blockIdx.x;
    int t = threadIdx.x;
    const float4* wrow = (const float4*)(Ws + (size_t)r * TOTAL);
    const float4* sv   = (const float4*)s_cur;
    float acc = 0.0f;
    #pragma unroll
    for (int k = 0; k < 8; k++) {
        float4 w  = wrow[t + 256 * k];
        float4 s4 = sv[t + 256 * k];
        acc += w.x * s4.x + w.y * s4.y + w.z * s4.z + w.w * s4.w;
    }
    __shared__ float red[4];
    for (int off = 32; off > 0; off >>= 1) acc += __shfl_down(acc, off, 64);
    if ((t & 63) == 0) red[t >> 6] = acc;
    __syncthreads();
    if (t == 0) {
        float g = red[0] + red[1] + red[2] + red[3];
        if (WITH_CORR && r >= H_SZ) g += corr[r - H_SZ];
        int i = I_SZ + r;
        s_next[i] = tanhf(s_cur[i] - LR * g);
    }
}

// ---------------- fallback path (small ws): no Wsym materialization ----------------
__global__ void k_rowmv(const float* __restrict__ W, const float* __restrict__ s_cur,
                        float* __restrict__ g_row) {
    int r = blockIdx.x;
    int t = threadIdx.x;
    const float4* wrow = (const float4*)(W + (size_t)(I_SZ + r) * TOTAL);
    const float4* sv   = (const float4*)s_cur;
    float acc = 0.0f;
    #pragma unroll
    for (int k = 0; k < 8; k++) {
        float4 w  = wrow[t + 256 * k];
        float4 s4 = sv[t + 256 * k];
        acc += w.x * s4.x + w.y * s4.y + w.z * s4.z + w.w * s4.w;
    }
    __shared__ float red[4];
    for (int off = 32; off > 0; off >>= 1) acc += __shfl_down(acc, off, 64);
    if ((t & 63) == 0) red[t >> 6] = acc;
    __syncthreads();
    if (t == 0) g_row[r] = red[0] + red[1] + red[2] + red[3];
}

__global__ void k_colmv(const float* __restrict__ W, const float* __restrict__ s_cur,
                        float* __restrict__ g_col) {
    int cl = blockIdx.x * 256 + threadIdx.x;  // 0..HO-1
    int c  = I_SZ + cl;
    int r0 = blockIdx.y * 256;
    float acc = 0.0f;
    for (int r = r0; r < r0 + 256; r++)
        acc += W[(size_t)r * TOTAL + c] * s_cur[r];
    atomicAdd(&g_col[cl], acc);
}

template <bool WITH_CORR>
__global__ void k_update(const float* __restrict__ g_row, const float* __restrict__ g_col,
                         const float* __restrict__ s_cur, float* __restrict__ s_next,
                         const float* __restrict__ corr) {
    int r = blockIdx.x * 256 + threadIdx.x;
    if (r >= HO) return;
    float g = 0.5f * (g_row[r] + g_col[r]);
    if (WITH_CORR && r >= H_SZ) g += corr[r - H_SZ];
    int i = I_SZ + r;
    s_next[i] = tanhf(s_cur[i] - LR * g);
}

extern "C" void kernel_launch(void* const* d_in, const int* in_sizes, int n_in,
                              void* d_out, int out_size, void* d_ws, size_t ws_size,
                              hipStream_t stream) {
    const float* W      = (const float*)d_in[0];
    const float* x      = (const float*)d_in[1];
    const float* target = (const float*)d_in[2];
    const float* mask   = (const float*)d_in[3];
    float* out = (float*)d_out;  // doubles as state buffer A
    char*  ws  = (char*)d_ws;

    const size_t ws_need = (size_t)HO * TOTAL * sizeof(float) + 65536;
    const bool fast = (ws_size >= ws_need);
    const int  STEPS = T1C + T2C;  // 24 (even -> final lands in d_out)

    if (fast) {
        float* Ws   = (float*)ws;
        float* s_b  = (float*)(ws + (size_t)HO * TOTAL * sizeof(float));
        float* corr = s_b + TOTAL;

        k_init<<<(TOTAL + 255) / 256, 256, 0, stream>>>(x, out, s_b);
        k_build<<<dim3(TOTAL / 32, HO / 32), dim3(32, 8), 0, stream>>>(W, Ws);

        const float* cur = out;
        float* nxt = s_b;
        for (int it = 0; it < STEPS; it++) {
            bool wc = (it >= T1C);
            if (wc) {
                k_softmax<<<1, 512, 0, stream>>>(cur, target, mask, corr);
                k_step<true><<<HO, 256, 0, stream>>>(Ws, cur, nxt, corr);
            } else {
                k_step<false><<<HO, 256, 0, stream>>>(Ws, cur, nxt, corr);
            }
            float* tmp = (float*)cur; cur = nxt; nxt = tmp;
        }
    } else {
        float* s_b   = (float*)ws;
        float* corr  = s_b + TOTAL;
        float* g_row = corr + O_SZ;
        float* g_col = g_row + HO;

        k_init<<<(TOTAL + 255) / 256, 256, 0, stream>>>(x, out, s_b);

        const float* cur = out;
        float* nxt = s_b;
        for (int it = 0; it < STEPS; it++) {
            bool wc = (it >= T1C);
            hipMemsetAsync(g_col, 0, HO * sizeof(float), stream);
            k_rowmv<<<HO, 256, 0, stream>>>(W, cur, g_row);
            k_colmv<<<dim3(HO / 256, TOTAL / 256), 256, 0, stream>>>(W, cur, g_col);
            if (wc) {
                k_softmax<<<1, 512, 0, stream>>>(cur, target, mask, corr);
                k_update<true><<<HO / 256, 256, 0, stream>>>(g_row, g_col, cur, nxt, corr);
            } else {
                k_update<false><<<HO / 256, 256, 0, stream>>>(g_row, g_col, cur, nxt, corr);
            }
            float* tmp = (float*)cur; cur = nxt; nxt = tmp;
        }
    }
}

// Round 3
// 638.586 us; speedup vs baseline: 1.3589x; 1.3589x over previous
//
#include <hip/hip_runtime.h>
#include <math.h>

#define I_SZ   4096
#define H_SZ   3584
#define O_SZ   512
#define TOTAL  8192
#define HO     4096   // TOTAL - I_SZ (rows that actually update)
#define BETA   0.1f
#define LR     0.5f
#define T1C    20
#define T2C    4

// ---------------- init: state buffers + zero b2 ----------------
__global__ void k_init(const float* __restrict__ x, float* __restrict__ s_a,
                       float* __restrict__ s_b, float* __restrict__ b2) {
    int i = blockIdx.x * 256 + threadIdx.x;
    if (i < I_SZ) { float v = x[i]; s_a[i] = v; s_b[i] = v; }
    else if (i < TOTAL) { s_a[i] = 0.0f; }
    if (i < HO) b2[i] = 0.0f;
}

// ---------------- build Wt = sym(W) lower-right block, 0.5 baked in ----------------
// Wt[r][c] = 0.5*(W[I_SZ+r][I_SZ+c] + W[I_SZ+c][I_SZ+r]),  r,c in [0,HO)
__global__ void k_build_wt(const float* __restrict__ W, float* __restrict__ Wt) {
    __shared__ float tb[32][33];
    int c0 = blockIdx.x * 32;
    int r0 = blockIdx.y * 32;
    int tx = threadIdx.x;   // 0..31
    int ty = threadIdx.y;   // 0..7
    #pragma unroll
    for (int k = 0; k < 4; k++) {
        int a = ty + 8 * k;
        tb[a][tx] = W[(size_t)(I_SZ + c0 + a) * TOTAL + (I_SZ + r0 + tx)];
    }
    __syncthreads();
    #pragma unroll
    for (int k = 0; k < 4; k++) {
        int ri = ty + 8 * k;
        int r = r0 + ri, c = c0 + tx;
        float direct = W[(size_t)(I_SZ + r) * TOTAL + (I_SZ + c)];
        Wt[(size_t)r * HO + c] = 0.5f * (direct + tb[tx][ri]);
    }
}

// ---------------- b1[r] = W[I_SZ+r][0:I_SZ] . x  (row part of constant term) ----------
__global__ void k_build_b1(const float* __restrict__ W, const float* __restrict__ x,
                           float* __restrict__ b1) {
    int r = blockIdx.x;
    int t = threadIdx.x;
    const float4* wrow = (const float4*)(W + (size_t)(I_SZ + r) * TOTAL);
    const float4* xv   = (const float4*)x;
    float acc = 0.0f;
    #pragma unroll
    for (int k = 0; k < 4; k++) {
        int idx = t + 256 * k;       // < 1024
        float4 w  = wrow[idx];
        float4 s4 = xv[idx];
        acc += w.x * s4.x + w.y * s4.y + w.z * s4.z + w.w * s4.w;
    }
    __shared__ float red[4];
    for (int off = 32; off > 0; off >>= 1) acc += __shfl_down(acc, off, 64);
    if ((t & 63) == 0) red[t >> 6] = acc;
    __syncthreads();
    if (t == 0) b1[r] = red[0] + red[1] + red[2] + red[3];
}

// ---------------- b2[c] = sum_j W[j][I_SZ+c]*x[j]  (transpose part, atomic) ----------
__global__ void k_build_b2(const float* __restrict__ W, const float* __restrict__ x,
                           float* __restrict__ b2) {
    int c  = blockIdx.x * 256 + threadIdx.x;   // 0..HO-1
    int j0 = blockIdx.y * 256;
    float acc = 0.0f;
    for (int j = j0; j < j0 + 256; j++)
        acc += W[(size_t)j * TOTAL + (I_SZ + c)] * x[j];
    atomicAdd(&b2[c], acc);
}

// ---------------- fused step: g = 0.5*(b1+b2) + Wt[r,:].s_tail (+ corr) --------------
template <bool BETA_STEP>
__global__ void k_step2(const float* __restrict__ Wt, const float* __restrict__ b1,
                        const float* __restrict__ b2, const float* __restrict__ s_cur,
                        float* __restrict__ s_next, const float* __restrict__ target,
                        const float* __restrict__ mask) {
    int r = blockIdx.x;
    int t = threadIdx.x;
    __shared__ float red[4];
    __shared__ float sm_m, sm_z, sm_ts;

    // --- inline softmax correction (only output-row blocks, beta phase) ---
    if (BETA_STEP && r >= H_SZ) {
        float l0 = s_cur[I_SZ + H_SZ + t];
        float l1 = s_cur[I_SZ + H_SZ + t + 256];
        float m = fmaxf(l0, l1);
        for (int off = 32; off > 0; off >>= 1) m = fmaxf(m, __shfl_down(m, off, 64));
        if ((t & 63) == 0) red[t >> 6] = m;
        __syncthreads();
        if (t == 0) sm_m = fmaxf(fmaxf(red[0], red[1]), fmaxf(red[2], red[3]));
        __syncthreads();
        float mm = sm_m;
        float z = expf(l0 - mm) + expf(l1 - mm);
        for (int off = 32; off > 0; off >>= 1) z += __shfl_down(z, off, 64);
        if ((t & 63) == 0) red[t >> 6] = z;
        __syncthreads();
        if (t == 0) sm_z = red[0] + red[1] + red[2] + red[3];
        float ts = mask[t] * target[t] + mask[t + 256] * target[t + 256];
        for (int off = 32; off > 0; off >>= 1) ts += __shfl_down(ts, off, 64);
        __syncthreads();
        if ((t & 63) == 0) red[t >> 6] = ts;
        __syncthreads();
        if (t == 0) sm_ts = red[0] + red[1] + red[2] + red[3];
        __syncthreads();
    }

    // --- 4096-wide dot: Wt row r (0.5 baked in) with s_tail ---
    const float4* wrow = (const float4*)(Wt + (size_t)r * HO);
    const float4* sv   = (const float4*)(s_cur + I_SZ);
    float acc = 0.0f;
    #pragma unroll
    for (int k = 0; k < 4; k++) {
        int idx = t + 256 * k;       // < 1024
        float4 w  = wrow[idx];
        float4 s4 = sv[idx];
        acc += w.x * s4.x + w.y * s4.y + w.z * s4.z + w.w * s4.w;
    }
    for (int off = 32; off > 0; off >>= 1) acc += __shfl_down(acc, off, 64);
    __syncthreads();   // protect red[] reuse
    if ((t & 63) == 0) red[t >> 6] = acc;
    __syncthreads();
    if (t == 0) {
        float g = 0.5f * (b1[r] + b2[r]) + red[0] + red[1] + red[2] + red[3];
        if (BETA_STEP && r >= H_SZ) {
            int j = r - H_SZ;
            float logit_own = s_cur[I_SZ + H_SZ + j];
            float p = expf(logit_own - sm_m) / sm_z;
            float te = mask[j] * target[j];
            g += -BETA * (p * sm_ts - te);
        }
        int i = I_SZ + r;
        s_next[i] = tanhf(s_cur[i] - LR * g);
    }
}

// ---------------- fallback path (small ws): fp32 two-pass, unchanged ----------------
__global__ void k_softmax(const float* __restrict__ s_cur,
                          const float* __restrict__ target,
                          const float* __restrict__ mask,
                          float* __restrict__ corr) {
    __shared__ float buf[8];
    __shared__ float s_m, s_z, s_ts;
    int t = threadIdx.x;  // 512 threads
    float logit = s_cur[I_SZ + H_SZ + t];
    float te = mask[t] * target[t];
    float m = logit;
    for (int off = 32; off > 0; off >>= 1) m = fmaxf(m, __shfl_down(m, off, 64));
    if ((t & 63) == 0) buf[t >> 6] = m;
    __syncthreads();
    if (t == 0) { float v = buf[0]; for (int i = 1; i < 8; i++) v = fmaxf(v, buf[i]); s_m = v; }
    __syncthreads();
    float e = expf(logit - s_m);
    float z = e;
    for (int off = 32; off > 0; off >>= 1) z += __shfl_down(z, off, 64);
    if ((t & 63) == 0) buf[t >> 6] = z;
    __syncthreads();
    if (t == 0) { float v = 0.f; for (int i = 0; i < 8; i++) v += buf[i]; s_z = v; }
    __syncthreads();
    float ts = te;
    for (int off = 32; off > 0; off >>= 1) ts += __shfl_down(ts, off, 64);
    if ((t & 63) == 0) buf[t >> 6] = ts;
    __syncthreads();
    if (t == 0) { float v = 0.f; for (int i = 0; i < 8; i++) v += buf[i]; s_ts = v; }
    __syncthreads();
    float p = e / s_z;
    corr[t] = -BETA * (p * s_ts - te);
}

__global__ void k_rowmv(const float* __restrict__ W, const float* __restrict__ s_cur,
                        float* __restrict__ g_row) {
    int r = blockIdx.x;
    int t = threadIdx.x;
    const float4* wrow = (const float4*)(W + (size_t)(I_SZ + r) * TOTAL);
    const float4* sv   = (const float4*)s_cur;
    float acc = 0.0f;
    #pragma unroll
    for (int k = 0; k < 8; k++) {
        float4 w  = wrow[t + 256 * k];
        float4 s4 = sv[t + 256 * k];
        acc += w.x * s4.x + w.y * s4.y + w.z * s4.z + w.w * s4.w;
    }
    __shared__ float red[4];
    for (int off = 32; off > 0; off >>= 1) acc += __shfl_down(acc, off, 64);
    if ((t & 63) == 0) red[t >> 6] = acc;
    __syncthreads();
    if (t == 0) g_row[r] = red[0] + red[1] + red[2] + red[3];
}

__global__ void k_colmv(const float* __restrict__ W, const float* __restrict__ s_cur,
                        float* __restrict__ g_col) {
    int cl = blockIdx.x * 256 + threadIdx.x;
    int c  = I_SZ + cl;
    int r0 = blockIdx.y * 256;
    float acc = 0.0f;
    for (int r = r0; r < r0 + 256; r++)
        acc += W[(size_t)r * TOTAL + c] * s_cur[r];
    atomicAdd(&g_col[cl], acc);
}

template <bool WITH_CORR>
__global__ void k_update(const float* __restrict__ g_row, const float* __restrict__ g_col,
                         const float* __restrict__ s_cur, float* __restrict__ s_next,
                         const float* __restrict__ corr) {
    int r = blockIdx.x * 256 + threadIdx.x;
    if (r >= HO) return;
    float g = 0.5f * (g_row[r] + g_col[r]);
    if (WITH_CORR && r >= H_SZ) g += corr[r - H_SZ];
    int i = I_SZ + r;
    s_next[i] = tanhf(s_cur[i] - LR * g);
}

extern "C" void kernel_launch(void* const* d_in, const int* in_sizes, int n_in,
                              void* d_out, int out_size, void* d_ws, size_t ws_size,
                              hipStream_t stream) {
    const float* W      = (const float*)d_in[0];
    const float* x      = (const float*)d_in[1];
    const float* target = (const float*)d_in[2];
    const float* mask   = (const float*)d_in[3];
    float* out = (float*)d_out;  // doubles as state buffer A
    char*  ws  = (char*)d_ws;

    const size_t WS_WT = (size_t)HO * HO * sizeof(float);   // 64 MB
    const size_t ws_need = WS_WT + 256 * 1024;
    const bool fast = (ws_size >= ws_need);
    const int  STEPS = T1C + T2C;  // 24 (even -> final lands in d_out)

    if (fast) {
        float* Wt  = (float*)ws;
        float* b1  = (float*)(ws + WS_WT);
        float* b2  = b1 + HO;
        float* s_b = b2 + HO;

        k_init<<<(TOTAL + 255) / 256, 256, 0, stream>>>(x, out, s_b, b2);
        k_build_wt<<<dim3(HO / 32, HO / 32), dim3(32, 8), 0, stream>>>(W, Wt);
        k_build_b1<<<HO, 256, 0, stream>>>(W, x, b1);
        k_build_b2<<<dim3(HO / 256, I_SZ / 256), 256, 0, stream>>>(W, x, b2);

        const float* cur = out;
        float* nxt = s_b;
        for (int it = 0; it < STEPS; it++) {
            if (it >= T1C) {
                k_step2<true><<<HO, 256, 0, stream>>>(Wt, b1, b2, cur, nxt, target, mask);
            } else {
                k_step2<false><<<HO, 256, 0, stream>>>(Wt, b1, b2, cur, nxt, target, mask);
            }
            float* tmp = (float*)cur; cur = nxt; nxt = tmp;
        }
    } else {
        float* s_b   = (float*)ws;
        float* corr  = s_b + TOTAL;
        float* g_row = corr + O_SZ;
        float* g_col = g_row + HO;

        k_init<<<(TOTAL + 255) / 256, 256, 0, stream>>>(x, out, s_b, g_col);

        const float* cur = out;
        float* nxt = s_b;
        for (int it = 0; it < STEPS; it++) {
            bool wc = (it >= T1C);
            hipMemsetAsync(g_col, 0, HO * sizeof(float), stream);
            k_rowmv<<<HO, 256, 0, stream>>>(W, cur, g_row);
            k_colmv<<<dim3(HO / 256, TOTAL / 256), 256, 0, stream>>>(W, cur, g_col);
            if (wc) {
                k_softmax<<<1, 512, 0, stream>>>(cur, target, mask, corr);
                k_update<true><<<HO / 256, 256, 0, stream>>>(g_row, g_col, cur, nxt, corr);
            } else {
                k_update<false><<<HO / 256, 256, 0, stream>>>(g_row, g_col, cur, nxt, corr);
            }
            float* tmp = (float*)cur; cur = nxt; nxt = tmp;
        }
    }
}